// Round 10
// baseline (386.686 us; speedup 1.0000x reference)
//
#include <hip/hip_runtime.h>

#define B_TOT 8192
#define T_OBS 128
#define T_FUT 64
#define T_ALL 192
#define DIN 5
#define HD 128
#define BT 16          // batch rows per block (ONE 16-row tile)
#define LDSTR 136      // LDS row stride in shorts (272 B, 16B-aligned rows)

#define LOG2E 1.44269504088896340736f

typedef __attribute__((ext_vector_type(8))) short short8;
typedef __attribute__((ext_vector_type(4))) float f32x4;
typedef __attribute__((ext_vector_type(2))) unsigned int u32x2;
typedef __attribute__((ext_vector_type(4))) unsigned int u32x4;

__device__ inline short f2bf(float f) {
    unsigned u = __float_as_uint(f);
    u += 0x7FFFu + ((u >> 16) & 1u);   // round-to-nearest-even
    return (short)(u >> 16);
}

// packed f32->bf16 (RNE), lo <- s0, hi <- s1
__device__ inline unsigned cvtpk(float lo, float hi) {
    unsigned r;
    asm volatile("v_cvt_pk_bf16_f32 %0, %1, %2" : "=v"(r) : "v"(lo), "v"(hi));
    return r;
}

__device__ inline f32x4 MFMA(short8 a, short8 b, f32x4 c) {
    return __builtin_amdgcn_mfma_f32_16x16x32_bf16(a, b, c, 0, 0, 0);
}

__device__ inline short8 load_w8s(const float* p, float s) {
    float4 a = *reinterpret_cast<const float4*>(p);
    float4 b = *reinterpret_cast<const float4*>(p + 4);
    short8 r;
    r[0] = f2bf(a.x * s); r[1] = f2bf(a.y * s); r[2] = f2bf(a.z * s); r[3] = f2bf(a.w * s);
    r[4] = f2bf(b.x * s); r[5] = f2bf(b.y * s); r[6] = f2bf(b.z * s); r[7] = f2bf(b.w * s);
    return r;
}
__device__ inline short8 load_w5s(const float* p, float s) {
    short8 r = (short8)0;
    r[0] = f2bf(p[0] * s); r[1] = f2bf(p[1] * s); r[2] = f2bf(p[2] * s);
    r[3] = f2bf(p[3] * s); r[4] = f2bf(p[4] * s);
    return r;
}

// 512 threads = 8 waves, BT=16 -> 512 blocks. TARGET: 2 blocks/CU
// (16 waves/CU, 4/SIMD) so the two blocks' INDEPENDENT barriers let one
// block issue while the other drains its serial chain.
//
// Register accounting (the lever): R1 proved 2x512-thr blocks DO co-reside
// at 64 arch VGPR (occupancy 46%); R2 failed at arch=100 because the MFMA
// accumulators live in AGPRs (~32, invisible in VGPR_Count) -> total ~132
// > 2048/16 = 128. This version removes ~36 arch regs vs R2: biases in
// per-wave LDS slots (f32, 4 broadcast b128 reads/step) and head weights
// + head bias in LDS (validated correct in R5-R7, absmax 0.0039).
// Per-wave arch estimate: 60 (15 short8 weights) + 16 (ah) + 4 (hreg) +
// 5 (x5) + ~10 addr ~= 95; + ~20 AGPR acc -> ~115 <= 128.
// launch_bounds(512,2): proven to produce arch<=100 for this structure.
//
// x-prefetch global loads are issued EARLY (right after the ah reads) so
// their latency hides under the step's compute before the next barrier's
// vmcnt drain.
__global__ __launch_bounds__(512, 2)
void gru_tracemodel_kernel(const float* __restrict__ obs, const float* __restrict__ target,
                           const float* __restrict__ eWih, const float* __restrict__ eWhh,
                           const float* __restrict__ ebih, const float* __restrict__ ebhh,
                           const float* __restrict__ cWih, const float* __restrict__ cWhh,
                           const float* __restrict__ cbih, const float* __restrict__ cbhh,
                           const float* __restrict__ headW, const float* __restrict__ headb,
                           float* __restrict__ out)
{
    __shared__ __attribute__((aligned(16))) short Abuf[2][BT][LDSTR];
    __shared__ __attribute__((aligned(16))) short Hw[DIN][LDSTR];      // head W, bf16
    __shared__ __attribute__((aligned(16))) float BiasLds[8][4][4][4]; // [wave][g][q][r]
    __shared__ float HbLds[8];

    const int tid   = threadIdx.x;
    const int wave  = tid >> 6;    // 0..7
    const int lane  = tid & 63;
    const int q     = lane >> 4;   // k-group of A/B frags; row-group of C/D
    const int c     = lane & 15;   // non-K index of A/B frags; col of C/D
    const int b0    = blockIdx.x * BT;
    const int wbase = wave * 16;   // this wave's gate-column slice

    // h0 = 0
    for (int i = tid; i < 2 * BT * LDSTR; i += 512) ((short*)Abuf)[i] = 0;

    // ---- weight fragments (A-operand: lane holds W'[n = wbase+c][k]) ----
    // kt 0..3: Whh K-tiles; kt 4: zero-padded Wih x-tile (only q==0 nonzero)
    short8 Wr[5], Wz[5], Wn[5];

    auto load_phase = [&](const float* Wih, const float* Whh,
                          const float* bih, const float* bhh) {
        const int nr = 0 * HD + wbase + c;
        const int nz = 1 * HD + wbase + c;
        const int nn = 2 * HD + wbase + c;
        #pragma unroll
        for (int kt = 0; kt < 4; ++kt) {
            Wr[kt] = load_w8s(Whh + nr * HD + kt * 32 + q * 8, LOG2E);
            Wz[kt] = load_w8s(Whh + nz * HD + kt * 32 + q * 8, LOG2E);
            Wn[kt] = load_w8s(Whh + nn * HD + kt * 32 + q * 8, 2.f * LOG2E);
        }
        Wr[4] = (q == 0) ? load_w5s(Wih + nr * DIN, LOG2E) : (short8)0;
        Wz[4] = (q == 0) ? load_w5s(Wih + nz * DIN, LOG2E) : (short8)0;
        Wn[4] = (q == 0) ? load_w5s(Wih + nn * DIN, 2.f * LOG2E) : (short8)0;
        // biases -> this wave's LDS slot (f32, exact); lane c==0 of each q.
        // Written and read only by this wave; compiler-inserted lgkmcnt
        // orders the within-wave write->read (no barrier needed).
        if (c == 0) {
            const int n0 = wbase + q * 4;
            f32x4 v0, v1, v2, v3;
            #pragma unroll
            for (int r = 0; r < 4; ++r) {
                v0[r] = (bih[0 * HD + n0 + r] + bhh[0 * HD + n0 + r]) * LOG2E;
                v1[r] = (bih[1 * HD + n0 + r] + bhh[1 * HD + n0 + r]) * LOG2E;
                v2[r] = bih[2 * HD + n0 + r] * (2.f * LOG2E);
                v3[r] = bhh[2 * HD + n0 + r] * (2.f * LOG2E);
            }
            *reinterpret_cast<f32x4*>(&BiasLds[wave][0][q][0]) = v0;
            *reinterpret_cast<f32x4*>(&BiasLds[wave][1][q][0]) = v1;
            *reinterpret_cast<f32x4*>(&BiasLds[wave][2][q][0]) = v2;
            *reinterpret_cast<f32x4*>(&BiasLds[wave][3][q][0]) = v3;
        }
    };
    load_phase(eWih, eWhh, ebih, ebhh);

    // head weights -> LDS once (wave 0); first read is at t>=T_OBS+1,
    // far behind many barriers.
    if (wave == 0 && c < DIN) {
        #pragma unroll
        for (int kt = 0; kt < 4; ++kt) {
            short8 w = load_w8s(headW + c * HD + kt * 32 + q * 8, 1.f);
            *reinterpret_cast<short8*>(&Hw[c][kt * 32 + q * 8]) = w;
        }
    }
    if (tid < 8) HbLds[tid] = (tid < DIN) ? headb[tid] : 0.f;

    // fp32 carried h: hreg[r] = h[batch c][gate-dim wbase+q*4+r]
    float hreg[4] = {0.f, 0.f, 0.f, 0.f};

    const float* obsr = obs    + (size_t)(b0 + c) * (T_OBS * DIN);
    const float* tgtr = target + (size_t)(b0 + c) * (T_FUT * DIN);
    float x5[5] = {0, 0, 0, 0, 0};
    if (q == 0) {
        #pragma unroll
        for (int j = 0; j < DIN; ++j) x5[j] = obsr[j];   // x_0
    }

    for (int t = 0; t <= T_ALL; ++t) {
        __syncthreads();
        const int p = t & 1;

        // h fragments (B-operand): lane holds h[batch c][k = kt*32+q*8..]
        short8 ah[4];
        const short* ap = &Abuf[p][c][0];
        #pragma unroll
        for (int kt = 0; kt < 4; ++kt)
            ah[kt] = *reinterpret_cast<const short8*>(ap + kt * 32 + q * 8);

        if (t == T_ALL) {
            // final head fire happens below via the rotating-wave branch;
            // but t==T_ALL only needs the head, handled before this break
            // in program order -- so fall through to head then break.
        }

        // x fragment: pack CURRENT x5, then issue next step's prefetch
        // loads EARLY so they complete well before the next barrier's
        // vmcnt drain. x5 is zero-initialized for q>=1 lanes, so the
        // unmasked cvtpk feeds exact zeros to the zeroed weight K-rows.
        short8 ax;
        if (t < T_ALL) {
            u32x4 va = { cvtpk(x5[0], x5[1]),
                         cvtpk(x5[2], x5[3]),
                         cvtpk(x5[4], 0.f), 0u };
            ax = __builtin_bit_cast(short8, va);
            const int tn = t + 1;
            if (q == 0 && tn < T_ALL) {
                const float* px = (tn < T_OBS)  ? (obsr + tn * DIN)
                                : (tn == T_OBS) ? (obsr + (T_OBS - 1) * DIN)
                                                : (tgtr + (tn - T_OBS - 1) * DIN);
                #pragma unroll
                for (int j = 0; j < DIN; ++j) x5[j] = px[j];
            }
        }

        // fused head on previous step's h; firing wave rotates over the
        // 8 gate-col slices to balance skew
        if (t >= T_OBS + 1 && wave == ((t - T_OBS - 1) & 7)) {
            const int s = t - (T_OBS + 1);
            const short* hwp = &Hw[(c < DIN) ? c : 0][0];
            f32x4 acc = {0.f, 0.f, 0.f, 0.f};
            #pragma unroll
            for (int kt = 0; kt < 4; ++kt) {
                short8 wh = *reinterpret_cast<const short8*>(hwp + kt * 32 + q * 8);
                acc = MFMA(wh, ah[kt], acc);
            }
            const int d0 = q * 4;
            if (d0 < DIN) {
                float* op = out + ((size_t)(b0 + c) * T_FUT + s) * DIN + d0;
                op[0] = acc[0] + HbLds[d0];
                if (q == 0) {
                    op[1] = acc[1] + HbLds[1];
                    op[2] = acc[2] + HbLds[2];
                    op[3] = acc[3] + HbLds[3];
                }
            }
        }
        if (t == T_ALL) break;

        if (t == T_OBS) load_phase(cWih, cWhh, cbih, cbhh);  // switch to cell

        // bias C-init: per-wave LDS broadcast reads (same addr across lanes
        // of each q-group -> conflict-free broadcast)
        const f32x4 bR  = *reinterpret_cast<const f32x4*>(&BiasLds[wave][0][q][0]);
        const f32x4 bZ  = *reinterpret_cast<const f32x4*>(&BiasLds[wave][1][q][0]);
        const f32x4 bNi = *reinterpret_cast<const f32x4*>(&BiasLds[wave][2][q][0]);
        const f32x4 bNh = *reinterpret_cast<const f32x4*>(&BiasLds[wave][3][q][0]);

        // gate MFMAs (A = weights, B = h): 15/wave/step
        f32x4 aR  = MFMA(Wr[0], ah[0], bR);
        f32x4 aZ  = MFMA(Wz[0], ah[0], bZ);
        f32x4 aNh = MFMA(Wn[0], ah[0], bNh);
        #pragma unroll
        for (int kt = 1; kt < 4; ++kt) {
            aR  = MFMA(Wr[kt], ah[kt], aR);
            aZ  = MFMA(Wz[kt], ah[kt], aZ);
            aNh = MFMA(Wn[kt], ah[kt], aNh);
        }
        aR  = MFMA(Wr[4], ax, aR);
        aZ  = MFMA(Wz[4], ax, aZ);
        f32x4 aNi = MFMA(Wn[4], ax, bNi);

        // elementwise: accumulators pre-scaled by log2e (2log2e for n).
        // rv = 1/(1+exp2(-aR)); y = aNi + rv*aNh; ey = exp2(y);
        // ez = exp2(-aZ);  h' = (h*(1+ey) + ez*(ey-1)) / ((1+ez)*(1+ey))
        // 3 exp2 + 2 rcp per element (validated R4-R9, absmax 0.0039).
        float hn[4];
        #pragma unroll
        for (int r = 0; r < 4; ++r) {
            float er  = __builtin_amdgcn_exp2f(-aR[r]);
            float rv  = __builtin_amdgcn_rcpf(1.f + er);
            float yv  = fmaf(rv, aNh[r], aNi[r]);
            float ey  = __builtin_amdgcn_exp2f(yv);
            float ez  = __builtin_amdgcn_exp2f(-aZ[r]);
            float d2  = 1.f + ey;
            float d1  = 1.f + ez;
            float em1 = ey - 1.f;
            float num = fmaf(ez, em1, hreg[r] * d2);
            float h_  = num * __builtin_amdgcn_rcpf(d1 * d2);
            hreg[r] = h_;
            hn[r] = h_;
        }
        // writeback: 4 consecutive gate-dims of one row -> one b64 store
        u32x2 wv = { cvtpk(hn[0], hn[1]), cvtpk(hn[2], hn[3]) };
        *reinterpret_cast<u32x2*>(&Abuf[1 - p][c][wbase + q * 4]) = wv;
    }
}

extern "C" void kernel_launch(void* const* d_in, const int* in_sizes, int n_in,
                              void* d_out, int out_size, void* d_ws, size_t ws_size,
                              hipStream_t stream)
{
    (void)in_sizes; (void)n_in; (void)d_ws; (void)ws_size; (void)out_size;
    gru_tracemodel_kernel<<<dim3(B_TOT / BT), dim3(512), 0, stream>>>(
        (const float*)d_in[0],  (const float*)d_in[1],
        (const float*)d_in[2],  (const float*)d_in[3],
        (const float*)d_in[4],  (const float*)d_in[5],
        (const float*)d_in[6],  (const float*)d_in[7],
        (const float*)d_in[8],  (const float*)d_in[9],
        (const float*)d_in[10], (const float*)d_in[11],
        (float*)d_out);
}

// Round 11
// 362.843 us; speedup vs baseline: 1.0657x; 1.0657x over previous
//
#include <hip/hip_runtime.h>

#define B_TOT 8192
#define T_OBS 128
#define T_FUT 64
#define T_ALL 192
#define DIN 5
#define HD 128
#define BT 32          // batch rows per block (two 16-row tiles)
#define LDSTR 136      // LDS row stride in shorts (272 B; cols 0..255 used)

#define LOG2E 1.44269504088896340736f

typedef __attribute__((ext_vector_type(8))) short short8;
typedef __attribute__((ext_vector_type(4))) float f32x4;
typedef __attribute__((ext_vector_type(2))) unsigned int u32x2;
typedef __attribute__((ext_vector_type(4))) unsigned int u32x4;

__device__ inline short f2bf(float f) {
    unsigned u = __float_as_uint(f);
    u += 0x7FFFu + ((u >> 16) & 1u);   // round-to-nearest-even
    return (short)(u >> 16);
}

// packed f32->bf16 (RNE), lo <- s0, hi <- s1
__device__ inline unsigned cvtpk(float lo, float hi) {
    unsigned r;
    asm volatile("v_cvt_pk_bf16_f32 %0, %1, %2" : "=v"(r) : "v"(lo), "v"(hi));
    return r;
}

__device__ inline f32x4 MFMA(short8 a, short8 b, f32x4 c) {
    return __builtin_amdgcn_mfma_f32_16x16x32_bf16(a, b, c, 0, 0, 0);
}

__device__ inline short8 load_w8s(const float* p, float s) {
    float4 a = *reinterpret_cast<const float4*>(p);
    float4 b = *reinterpret_cast<const float4*>(p + 4);
    short8 r;
    r[0] = f2bf(a.x * s); r[1] = f2bf(a.y * s); r[2] = f2bf(a.z * s); r[3] = f2bf(a.w * s);
    r[4] = f2bf(b.x * s); r[5] = f2bf(b.y * s); r[6] = f2bf(b.z * s); r[7] = f2bf(b.w * s);
    return r;
}
__device__ inline short8 load_w5s(const float* p, float s) {
    short8 r = (short8)0;
    r[0] = f2bf(p[0] * s); r[1] = f2bf(p[1] * s); r[2] = f2bf(p[2] * s);
    r[3] = f2bf(p[3] * s); r[4] = f2bf(p[4] * s);
    return r;
}

// 512 threads = 8 waves, 256 blocks = 1 block/CU (R9 anchor, 289 us).
// CLOSED PATHS (hard evidence, do not revisit): >8 waves/CU configs spill
// (64-VGPR wall: R1/R4/R5/R6/R7); 2x512-thr co-residency fails for any
// VGPR>64 (R2/R10, occupancy pinned 23%).
//
// R11 delta: XOR-swizzled Abuf. Row stride 272 B = 4 dwords (mod 32), so
// unswizzled lane reads stack 8 lanes per 4-bank group (measured 1.58e7
// conflict cycles/dispatch = ~320 cyc/CU-step on top of the 512-cyc LDS
// port floor). phys_col = col ^ ((row&7)<<4) on BOTH ds_write and ds_read
// spreads starts uniformly (8 dwords/bank = wave64 floor). Addresses are
// loop-invariant (only buffer parity flips) -> zero steady-state cost.
// Also: x prefetch as float4+float (2 loads vs 5 scalars).
__global__ __launch_bounds__(512, 1)
void gru_tracemodel_kernel(const float* __restrict__ obs, const float* __restrict__ target,
                           const float* __restrict__ eWih, const float* __restrict__ eWhh,
                           const float* __restrict__ ebih, const float* __restrict__ ebhh,
                           const float* __restrict__ cWih, const float* __restrict__ cWhh,
                           const float* __restrict__ cbih, const float* __restrict__ cbhh,
                           const float* __restrict__ headW, const float* __restrict__ headb,
                           float* __restrict__ out)
{
    __shared__ __attribute__((aligned(16))) short Abuf[2][BT][LDSTR];

    const int tid   = threadIdx.x;
    const int wave  = tid >> 6;    // 0..7
    const int lane  = tid & 63;
    const int q     = lane >> 4;   // k-group of A/B frags; row-group of C/D
    const int c     = lane & 15;   // non-K index of A/B frags; col of C/D
    const int b0    = blockIdx.x * BT;
    const int wbase = wave * 16;   // this wave's gate-column slice
    const int sw    = (c & 7) << 4; // XOR swizzle term (row&7 == c&7 here)

    // h0 = 0 (raw linear zero fill; zero is swizzle-agnostic)
    for (int i = tid; i < 2 * BT * LDSTR; i += 512) ((short*)Abuf)[i] = 0;

    // ---- weight fragments (A-operand: lane holds W'[n = wbase+c][k]) ----
    // kt 0..3: Whh K-tiles; kt 4: zero-padded Wih x-tile (only q==0 nonzero)
    short8 Wr[5], Wz[5], Wn[5];
    f32x4  br4, bz4, bnh4, bni4;   // per-reg biases: n = wbase + q*4 + r

    auto load_phase = [&](const float* Wih, const float* Whh,
                          const float* bih, const float* bhh) {
        const int nr = 0 * HD + wbase + c;
        const int nz = 1 * HD + wbase + c;
        const int nn = 2 * HD + wbase + c;
        #pragma unroll
        for (int kt = 0; kt < 4; ++kt) {
            Wr[kt] = load_w8s(Whh + nr * HD + kt * 32 + q * 8, LOG2E);
            Wz[kt] = load_w8s(Whh + nz * HD + kt * 32 + q * 8, LOG2E);
            Wn[kt] = load_w8s(Whh + nn * HD + kt * 32 + q * 8, 2.f * LOG2E);
        }
        Wr[4] = (q == 0) ? load_w5s(Wih + nr * DIN, LOG2E) : (short8)0;
        Wz[4] = (q == 0) ? load_w5s(Wih + nz * DIN, LOG2E) : (short8)0;
        Wn[4] = (q == 0) ? load_w5s(Wih + nn * DIN, 2.f * LOG2E) : (short8)0;
        const int n0 = wbase + q * 4;
        #pragma unroll
        for (int r = 0; r < 4; ++r) {
            br4[r]  = (bih[0 * HD + n0 + r] + bhh[0 * HD + n0 + r]) * LOG2E;
            bz4[r]  = (bih[1 * HD + n0 + r] + bhh[1 * HD + n0 + r]) * LOG2E;
            bni4[r] = bih[2 * HD + n0 + r] * (2.f * LOG2E);
            bnh4[r] = bhh[2 * HD + n0 + r] * (2.f * LOG2E);
        }
    };
    load_phase(eWih, eWhh, ebih, ebhh);

    // head fragments (all waves hold them; firing wave rotates per step).
    short8 Whd[4];
    f32x4  hb4;
    #pragma unroll
    for (int kt = 0; kt < 4; ++kt)
        Whd[kt] = (c < DIN) ? load_w8s(headW + c * HD + kt * 32 + q * 8, 1.f) : (short8)0;
    #pragma unroll
    for (int r = 0; r < 4; ++r)
        hb4[r] = (q * 4 + r < DIN) ? headb[q * 4 + r] : 0.f;

    // fp32 carried h: hreg[a][r] = h[batch a*16+c][gate-dim wbase+q*4+r]
    float hreg[2][4] = {{0.f,0.f,0.f,0.f},{0.f,0.f,0.f,0.f}};

    const float* obsr[2] = { obs + (size_t)(b0 + c) * (T_OBS * DIN),
                             obs + (size_t)(b0 + 16 + c) * (T_OBS * DIN) };
    const float* tgtr[2] = { target + (size_t)(b0 + c) * (T_FUT * DIN),
                             target + (size_t)(b0 + 16 + c) * (T_FUT * DIN) };
    float x5[2][5] = {{0,0,0,0,0},{0,0,0,0,0}};
    if (q == 0) {
        #pragma unroll
        for (int a = 0; a < 2; ++a) {
            float4 v4 = *reinterpret_cast<const float4*>(obsr[a]);
            x5[a][0] = v4.x; x5[a][1] = v4.y; x5[a][2] = v4.z; x5[a][3] = v4.w;
            x5[a][4] = obsr[a][4];
        }
    }

    // loop-invariant swizzled LDS addresses (parity handled by p*HALF)
    const char* rbase[2] = { (const char*)&Abuf[0][c][0],
                             (const char*)&Abuf[0][16 + c][0] };
    char* wbasep[2] = { (char*)&Abuf[0][c][0] + ((wave * 32 + q * 8) ^ sw),
                        (char*)&Abuf[0][16 + c][0] + ((wave * 32 + q * 8) ^ sw) };
    const int HALF = BT * LDSTR * 2;   // bytes per buffer

    for (int t = 0; t <= T_ALL; ++t) {
        __syncthreads();
        const int p = t & 1;
        const int po = p * HALF;
        const int wo = (1 - p) * HALF;

        // h fragments (B-operand), swizzled reads:
        // lane reads h[row a*16+c][k = kt*32+q*8 .. +8]
        short8 ah[2][4];
        #pragma unroll
        for (int a = 0; a < 2; ++a)
            #pragma unroll
            for (int kt = 0; kt < 4; ++kt)
                ah[a][kt] = *reinterpret_cast<const short8*>(
                    rbase[a] + po + ((kt * 64 + q * 16) ^ sw));

        // fused head on previous step's h; firing wave rotates to balance skew
        if (t >= T_OBS + 1 && wave == ((t - T_OBS - 1) & 7)) {
            const int s = t - (T_OBS + 1);
            const int d0 = q * 4;
            #pragma unroll
            for (int a = 0; a < 2; ++a) {
                f32x4 acc = hb4;
                #pragma unroll
                for (int kt = 0; kt < 4; ++kt)
                    acc = MFMA(Whd[kt], ah[a][kt], acc);
                // D[d = q*4+r][batch = a*16+c]
                if (d0 < DIN) {
                    float* op = out + ((size_t)(b0 + a * 16 + c) * T_FUT + s) * DIN + d0;
                    op[0] = acc[0];
                    if (q == 0) { op[1] = acc[1]; op[2] = acc[2]; op[3] = acc[3]; }
                }
            }
        }
        if (t == T_ALL) break;

        if (t == T_OBS) load_phase(cWih, cWhh, cbih, cbhh);  // switch to cell

        // x fragment (5th K-tile, B-operand). cvtpk runs unmasked: q>=1
        // lanes hold zero-init x5 -> exact zeros into zeroed weight K-rows.
        short8 ax[2];
        {
            u32x4 va = { cvtpk(x5[0][0], x5[0][1]),
                         cvtpk(x5[0][2], x5[0][3]),
                         cvtpk(x5[0][4], 0.f), 0u };
            u32x4 vb = { cvtpk(x5[1][0], x5[1][1]),
                         cvtpk(x5[1][2], x5[1][3]),
                         cvtpk(x5[1][4], 0.f), 0u };
            ax[0] = __builtin_bit_cast(short8, va);
            ax[1] = __builtin_bit_cast(short8, vb);
            const int tn = t + 1;   // prefetch next step's x (masked loads)
            if (q == 0 && tn < T_ALL) {
                #pragma unroll
                for (int a = 0; a < 2; ++a) {
                    const float* px = (tn < T_OBS)  ? (obsr[a] + tn * DIN)
                                    : (tn == T_OBS) ? (obsr[a] + (T_OBS - 1) * DIN)
                                                    : (tgtr[a] + (tn - T_OBS - 1) * DIN);
                    float4 v4 = *reinterpret_cast<const float4*>(px);
                    x5[a][0] = v4.x; x5[a][1] = v4.y;
                    x5[a][2] = v4.z; x5[a][3] = v4.w;
                    x5[a][4] = px[4];
                }
            }
        }

        // gate MFMAs (A = weights, B = h): 30/wave/step
        #pragma unroll
        for (int a = 0; a < 2; ++a) {
            f32x4 aR  = MFMA(Wr[0], ah[a][0], br4);
            f32x4 aZ  = MFMA(Wz[0], ah[a][0], bz4);
            f32x4 aNh = MFMA(Wn[0], ah[a][0], bnh4);
            #pragma unroll
            for (int kt = 1; kt < 4; ++kt) {
                aR  = MFMA(Wr[kt], ah[a][kt], aR);
                aZ  = MFMA(Wz[kt], ah[a][kt], aZ);
                aNh = MFMA(Wn[kt], ah[a][kt], aNh);
            }
            aR  = MFMA(Wr[4], ax[a], aR);
            aZ  = MFMA(Wz[4], ax[a], aZ);
            f32x4 aNi = MFMA(Wn[4], ax[a], bni4);

            // elementwise: accumulators pre-scaled by log2e (2log2e for n).
            // rv = 1/(1+exp2(-aR)); y = aNi + rv*aNh; ey = exp2(y);
            // ez = exp2(-aZ);  h' = (h*(1+ey) + ez*(ey-1)) / ((1+ez)*(1+ey))
            // 3 exp2 + 2 rcp per element (validated R4-R9, absmax 0.0039).
            float hn[4];
            #pragma unroll
            for (int r = 0; r < 4; ++r) {
                float er  = __builtin_amdgcn_exp2f(-aR[r]);
                float rv  = __builtin_amdgcn_rcpf(1.f + er);
                float yv  = fmaf(rv, aNh[r], aNi[r]);
                float ey  = __builtin_amdgcn_exp2f(yv);
                float ez  = __builtin_amdgcn_exp2f(-aZ[r]);
                float d2  = 1.f + ey;
                float d1  = 1.f + ez;
                float em1 = ey - 1.f;
                float num = fmaf(ez, em1, hreg[a][r] * d2);
                float h_  = num * __builtin_amdgcn_rcpf(d1 * d2);
                hreg[a][r] = h_;
                hn[r] = h_;
            }
            // writeback (swizzled): 4 consecutive gate-dims -> one b64 store
            u32x2 wv = { cvtpk(hn[0], hn[1]), cvtpk(hn[2], hn[3]) };
            *reinterpret_cast<u32x2*>(wbasep[a] + wo) = wv;
        }
    }
}

extern "C" void kernel_launch(void* const* d_in, const int* in_sizes, int n_in,
                              void* d_out, int out_size, void* d_ws, size_t ws_size,
                              hipStream_t stream)
{
    (void)in_sizes; (void)n_in; (void)d_ws; (void)ws_size; (void)out_size;
    gru_tracemodel_kernel<<<dim3(B_TOT / BT), dim3(512), 0, stream>>>(
        (const float*)d_in[0],  (const float*)d_in[1],
        (const float*)d_in[2],  (const float*)d_in[3],
        (const float*)d_in[4],  (const float*)d_in[5],
        (const float*)d_in[6],  (const float*)d_in[7],
        (const float*)d_in[8],  (const float*)d_in[9],
        (const float*)d_in[10], (const float*)d_in[11],
        (float*)d_out);
}

// Round 12
// 323.797 us; speedup vs baseline: 1.1942x; 1.1206x over previous
//
#include <hip/hip_runtime.h>

#define B_TOT 8192
#define T_OBS 128
#define T_FUT 64
#define T_ALL 192
#define DIN 5
#define HD 128
#define BT 32          // batch rows per block (two 16-row tiles)
#define LDSTR 136      // LDS row stride in shorts (272 B, 16B-aligned rows)

#define LOG2E 1.44269504088896340736f

typedef __attribute__((ext_vector_type(8))) short short8;
typedef __attribute__((ext_vector_type(4))) float f32x4;
typedef __attribute__((ext_vector_type(2))) unsigned int u32x2;
typedef __attribute__((ext_vector_type(4))) unsigned int u32x4;

__device__ inline short f2bf(float f) {
    unsigned u = __float_as_uint(f);
    u += 0x7FFFu + ((u >> 16) & 1u);   // round-to-nearest-even
    return (short)(u >> 16);
}

// packed f32->bf16 (RNE), lo <- s0, hi <- s1
__device__ inline unsigned cvtpk(float lo, float hi) {
    unsigned r;
    asm volatile("v_cvt_pk_bf16_f32 %0, %1, %2" : "=v"(r) : "v"(lo), "v"(hi));
    return r;
}

__device__ inline f32x4 MFMA(short8 a, short8 b, f32x4 c) {
    return __builtin_amdgcn_mfma_f32_16x16x32_bf16(a, b, c, 0, 0, 0);
}

__device__ inline short8 load_w8s(const float* p, float s) {
    float4 a = *reinterpret_cast<const float4*>(p);
    float4 b = *reinterpret_cast<const float4*>(p + 4);
    short8 r;
    r[0] = f2bf(a.x * s); r[1] = f2bf(a.y * s); r[2] = f2bf(a.z * s); r[3] = f2bf(a.w * s);
    r[4] = f2bf(b.x * s); r[5] = f2bf(b.y * s); r[6] = f2bf(b.z * s); r[7] = f2bf(b.w * s);
    return r;
}
__device__ inline short8 load_w5s(const float* p, float s) {
    short8 r = (short8)0;
    r[0] = f2bf(p[0] * s); r[1] = f2bf(p[1] * s); r[2] = f2bf(p[2] * s);
    r[3] = f2bf(p[3] * s); r[4] = f2bf(p[4] * s);
    return r;
}

// 512 threads = 8 waves, 256 blocks = 1 block/CU (R9 anchor layout, 289 us,
// VGPR=112 no-spill). Wave w owns gate-cols [16w,16w+16) of r/z/n; block
// owns 32 rows as two 16-row B-tiles. Swapped MFMA (A=weights, B=h^T).
//
// CLOSED PATHS (hard evidence, do not revisit):
//  - >8 waves/CU: 64-VGPR wall + ~600 MB scratch spill (R1/R4/R5/R6/R7).
//  - 2x512-thr co-residency: fails for VGPR>64 (R2/R10, occupancy 23%).
//  - LDS XOR swizzle of Abuf: reads are ALREADY conflict-free at the
//    8-lane port grouping; swizzle quadrupled conflicts (R11, 4.4x).
//    Residual 1.58e7 conflicts cost only ~8 us (R9/R11 A/B calibration).
//
// R12 deltas vs R9: (a) loop split encoder/transition/rollout/final -
// removes head-test, 3-way x-select, t==T_OBS/T_ALL checks from all 192
// steps; rollout prefetch is guard-free (idx t-128 <= 63 always valid);
// (b) float4 x-prefetch; (c) final head: only wave 7 reads ah.
__global__ __launch_bounds__(512, 1)
void gru_tracemodel_kernel(const float* __restrict__ obs, const float* __restrict__ target,
                           const float* __restrict__ eWih, const float* __restrict__ eWhh,
                           const float* __restrict__ ebih, const float* __restrict__ ebhh,
                           const float* __restrict__ cWih, const float* __restrict__ cWhh,
                           const float* __restrict__ cbih, const float* __restrict__ cbhh,
                           const float* __restrict__ headW, const float* __restrict__ headb,
                           float* __restrict__ out)
{
    __shared__ __attribute__((aligned(16))) short Abuf[2][BT][LDSTR];

    const int tid   = threadIdx.x;
    const int wave  = tid >> 6;    // 0..7
    const int lane  = tid & 63;
    const int q     = lane >> 4;   // k-group of A/B frags; row-group of C/D
    const int c     = lane & 15;   // non-K index of A/B frags; col of C/D
    const int b0    = blockIdx.x * BT;
    const int wbase = wave * 16;   // this wave's gate-column slice

    // h0 = 0
    for (int i = tid; i < 2 * BT * LDSTR; i += 512) ((short*)Abuf)[i] = 0;

    // ---- weight fragments (A-operand: lane holds W'[n = wbase+c][k]) ----
    // kt 0..3: Whh K-tiles; kt 4: zero-padded Wih x-tile (only q==0 nonzero)
    short8 Wr[5], Wz[5], Wn[5];
    f32x4  br4, bz4, bnh4, bni4;   // per-reg biases: n = wbase + q*4 + r

    auto load_phase = [&](const float* Wih, const float* Whh,
                          const float* bih, const float* bhh) {
        const int nr = 0 * HD + wbase + c;
        const int nz = 1 * HD + wbase + c;
        const int nn = 2 * HD + wbase + c;
        #pragma unroll
        for (int kt = 0; kt < 4; ++kt) {
            Wr[kt] = load_w8s(Whh + nr * HD + kt * 32 + q * 8, LOG2E);
            Wz[kt] = load_w8s(Whh + nz * HD + kt * 32 + q * 8, LOG2E);
            Wn[kt] = load_w8s(Whh + nn * HD + kt * 32 + q * 8, 2.f * LOG2E);
        }
        Wr[4] = (q == 0) ? load_w5s(Wih + nr * DIN, LOG2E) : (short8)0;
        Wz[4] = (q == 0) ? load_w5s(Wih + nz * DIN, LOG2E) : (short8)0;
        Wn[4] = (q == 0) ? load_w5s(Wih + nn * DIN, 2.f * LOG2E) : (short8)0;
        const int n0 = wbase + q * 4;
        #pragma unroll
        for (int r = 0; r < 4; ++r) {
            br4[r]  = (bih[0 * HD + n0 + r] + bhh[0 * HD + n0 + r]) * LOG2E;
            bz4[r]  = (bih[1 * HD + n0 + r] + bhh[1 * HD + n0 + r]) * LOG2E;
            bni4[r] = bih[2 * HD + n0 + r] * (2.f * LOG2E);
            bnh4[r] = bhh[2 * HD + n0 + r] * (2.f * LOG2E);
        }
    };
    load_phase(eWih, eWhh, ebih, ebhh);

    // head fragments (all waves hold them; firing wave rotates per step).
    short8 Whd[4];
    f32x4  hb4;
    #pragma unroll
    for (int kt = 0; kt < 4; ++kt)
        Whd[kt] = (c < DIN) ? load_w8s(headW + c * HD + kt * 32 + q * 8, 1.f) : (short8)0;
    #pragma unroll
    for (int r = 0; r < 4; ++r)
        hb4[r] = (q * 4 + r < DIN) ? headb[q * 4 + r] : 0.f;

    // fp32 carried h: hreg[a][r] = h[batch a*16+c][gate-dim wbase+q*4+r]
    float hreg[2][4] = {{0.f,0.f,0.f,0.f},{0.f,0.f,0.f,0.f}};

    const float* obsr[2] = { obs + (size_t)(b0 + c) * (T_OBS * DIN),
                             obs + (size_t)(b0 + 16 + c) * (T_OBS * DIN) };
    const float* tgtr[2] = { target + (size_t)(b0 + c) * (T_FUT * DIN),
                             target + (size_t)(b0 + 16 + c) * (T_FUT * DIN) };
    float x5[2][5] = {{0,0,0,0,0},{0,0,0,0,0}};
    if (q == 0) {
        #pragma unroll
        for (int a = 0; a < 2; ++a) {
            float4 v4 = *reinterpret_cast<const float4*>(obsr[a]);
            x5[a][0] = v4.x; x5[a][1] = v4.y; x5[a][2] = v4.z; x5[a][3] = v4.w;
            x5[a][4] = obsr[a][4];
        }
    }

// One GRU time step. T is runtime, DO_HEAD/ENC are 0/1 literals so dead
// branches fold at compile time in each loop region.
#define GRU_STEP(T, DO_HEAD, ENC)                                              \
  {                                                                            \
    __syncthreads();                                                           \
    const int p_ = (T) & 1;                                                    \
    short8 ah[2][4];                                                           \
    _Pragma("unroll")                                                          \
    for (int a = 0; a < 2; ++a) {                                              \
      const short* ap = &Abuf[p_][a * 16 + c][0];                              \
      _Pragma("unroll")                                                        \
      for (int kt = 0; kt < 4; ++kt)                                           \
        ah[a][kt] = *reinterpret_cast<const short8*>(ap + kt * 32 + q * 8);    \
    }                                                                          \
    if (DO_HEAD) {                                                             \
      const int s_ = (T) - (T_OBS + 1);                                        \
      if (wave == (s_ & 7)) {                                                  \
        const int d0 = q * 4;                                                  \
        _Pragma("unroll")                                                      \
        for (int a = 0; a < 2; ++a) {                                          \
          f32x4 acc = hb4;                                                     \
          _Pragma("unroll")                                                    \
          for (int kt = 0; kt < 4; ++kt)                                       \
            acc = MFMA(Whd[kt], ah[a][kt], acc);                               \
          if (d0 < DIN) {                                                      \
            float* op = out + ((size_t)(b0 + a * 16 + c) * T_FUT + s_) * DIN + d0; \
            op[0] = acc[0];                                                    \
            if (q == 0) { op[1] = acc[1]; op[2] = acc[2]; op[3] = acc[3]; }    \
          }                                                                    \
        }                                                                      \
      }                                                                        \
    }                                                                          \
    short8 ax[2];                                                              \
    {                                                                          \
      u32x4 va = { cvtpk(x5[0][0], x5[0][1]), cvtpk(x5[0][2], x5[0][3]),       \
                   cvtpk(x5[0][4], 0.f), 0u };                                 \
      u32x4 vb = { cvtpk(x5[1][0], x5[1][1]), cvtpk(x5[1][2], x5[1][3]),       \
                   cvtpk(x5[1][4], 0.f), 0u };                                 \
      ax[0] = __builtin_bit_cast(short8, va);                                  \
      ax[1] = __builtin_bit_cast(short8, vb);                                  \
      if (q == 0) {                                                            \
        const int tn_ = (T) + 1;                                               \
        _Pragma("unroll")                                                      \
        for (int a = 0; a < 2; ++a) {                                          \
          const float* px = (ENC)                                              \
              ? (obsr[a] + ((tn_ < T_OBS) ? tn_ : (T_OBS - 1)) * DIN)          \
              : (tgtr[a] + (tn_ - T_OBS - 1) * DIN);                           \
          float4 v4 = *reinterpret_cast<const float4*>(px);                    \
          x5[a][0] = v4.x; x5[a][1] = v4.y; x5[a][2] = v4.z; x5[a][3] = v4.w;  \
          x5[a][4] = px[4];                                                    \
        }                                                                      \
      }                                                                        \
    }                                                                          \
    _Pragma("unroll")                                                          \
    for (int a = 0; a < 2; ++a) {                                              \
      f32x4 aR  = MFMA(Wr[0], ah[a][0], br4);                                  \
      f32x4 aZ  = MFMA(Wz[0], ah[a][0], bz4);                                  \
      f32x4 aNh = MFMA(Wn[0], ah[a][0], bnh4);                                 \
      _Pragma("unroll")                                                        \
      for (int kt = 1; kt < 4; ++kt) {                                         \
        aR  = MFMA(Wr[kt], ah[a][kt], aR);                                     \
        aZ  = MFMA(Wz[kt], ah[a][kt], aZ);                                     \
        aNh = MFMA(Wn[kt], ah[a][kt], aNh);                                    \
      }                                                                        \
      aR  = MFMA(Wr[4], ax[a], aR);                                            \
      aZ  = MFMA(Wz[4], ax[a], aZ);                                            \
      f32x4 aNi = MFMA(Wn[4], ax[a], bni4);                                    \
      float hn[4];                                                             \
      _Pragma("unroll")                                                        \
      for (int r = 0; r < 4; ++r) {                                            \
        float er  = __builtin_amdgcn_exp2f(-aR[r]);                            \
        float rv  = __builtin_amdgcn_rcpf(1.f + er);                           \
        float yv  = fmaf(rv, aNh[r], aNi[r]);                                  \
        float ey  = __builtin_amdgcn_exp2f(yv);                                \
        float ez  = __builtin_amdgcn_exp2f(-aZ[r]);                            \
        float d2  = 1.f + ey;                                                  \
        float d1  = 1.f + ez;                                                  \
        float em1 = ey - 1.f;                                                  \
        float num = fmaf(ez, em1, hreg[a][r] * d2);                            \
        float h_  = num * __builtin_amdgcn_rcpf(d1 * d2);                      \
        hreg[a][r] = h_;                                                       \
        hn[r] = h_;                                                            \
      }                                                                        \
      u32x2 wv = { cvtpk(hn[0], hn[1]), cvtpk(hn[2], hn[3]) };                 \
      *reinterpret_cast<u32x2*>(&Abuf[1 - p_][a * 16 + c][wbase + q * 4]) = wv;\
    }                                                                          \
  }

    // encoder: t = 0..127 (no head; x from obs, clamped select for t=127)
    for (int t = 0; t < T_OBS; ++t) GRU_STEP(t, 0, 1);

    // transition: switch to cell weights (register-only; between barriers)
    load_phase(cWih, cWhh, cbih, cbhh);
    GRU_STEP(T_OBS, 0, 0);   // t = 128; prefetch target[0]

    // rollout: t = 129..191 (head fires for s = t-129; prefetch guard-free:
    // idx t-128 <= 63 is always a valid target row)
    for (int t = T_OBS + 1; t < T_ALL; ++t) GRU_STEP(t, 1, 0);

    // final: t = 192 -- head only, fired by wave 7 (s=63); other waves done
    __syncthreads();
    if (wave == ((T_FUT - 1) & 7)) {
        const int p_ = T_ALL & 1;
        const int s_ = T_FUT - 1;
        const int d0 = q * 4;
        #pragma unroll
        for (int a = 0; a < 2; ++a) {
            const short* ap = &Abuf[p_][a * 16 + c][0];
            f32x4 acc = hb4;
            #pragma unroll
            for (int kt = 0; kt < 4; ++kt) {
                short8 h8 = *reinterpret_cast<const short8*>(ap + kt * 32 + q * 8);
                acc = MFMA(Whd[kt], h8, acc);
            }
            if (d0 < DIN) {
                float* op = out + ((size_t)(b0 + a * 16 + c) * T_FUT + s_) * DIN + d0;
                op[0] = acc[0];
                if (q == 0) { op[1] = acc[1]; op[2] = acc[2]; op[3] = acc[3]; }
            }
        }
    }
#undef GRU_STEP
}

extern "C" void kernel_launch(void* const* d_in, const int* in_sizes, int n_in,
                              void* d_out, int out_size, void* d_ws, size_t ws_size,
                              hipStream_t stream)
{
    (void)in_sizes; (void)n_in; (void)d_ws; (void)ws_size; (void)out_size;
    gru_tracemodel_kernel<<<dim3(B_TOT / BT), dim3(512), 0, stream>>>(
        (const float*)d_in[0],  (const float*)d_in[1],
        (const float*)d_in[2],  (const float*)d_in[3],
        (const float*)d_in[4],  (const float*)d_in[5],
        (const float*)d_in[6],  (const float*)d_in[7],
        (const float*)d_in[8],  (const float*)d_in[9],
        (const float*)d_in[10], (const float*)d_in[11],
        (float*)d_out);
}